// Round 11
// baseline (124.761 us; speedup 1.0000x reference)
//
#include <hip/hip_runtime.h>
#include <math.h>

#define HW 16384
#define C_DIM 256
#define V_DIM 6
#define PT 64
#define BK 32
#define MROW 40   // padded row: 80 B = 20 words; all b128/uint4 LDS ops at bank floor

typedef short bf16x8 __attribute__((ext_vector_type(8)));
typedef float f32x4 __attribute__((ext_vector_type(4)));

// fp32 -> bf16 hi/lo split (truncation). |x - (hi+lo)| <= 2^-16 |x|.
__device__ __forceinline__ void split2(float x, unsigned short& h,
                                       unsigned short& l) {
    unsigned u = __float_as_uint(x);
    h = (unsigned short)(u >> 16);
    float xl = x - __uint_as_float(u & 0xFFFF0000u);
    l = (unsigned short)(__float_as_uint(xl) >> 16);
}

// ---------------------------------------------------------------------------
// K1: M = Wq^T @ Wk, stored as bf16 hi/lo.
// ---------------------------------------------------------------------------
__global__ void compute_M_kernel(const float* __restrict__ Wq,
                                 const float* __restrict__ Wk,
                                 unsigned short* __restrict__ Mh,
                                 unsigned short* __restrict__ Ml) {
    const int i = blockIdx.x;
    const int j = threadIdx.x;
    float a0 = 0.f, a1 = 0.f, a2 = 0.f, a3 = 0.f;
    #pragma unroll 4
    for (int o = 0; o < C_DIM; o += 4) {
        a0 = fmaf(Wq[(o + 0) * C_DIM + i], Wk[(o + 0) * C_DIM + j], a0);
        a1 = fmaf(Wq[(o + 1) * C_DIM + i], Wk[(o + 1) * C_DIM + j], a1);
        a2 = fmaf(Wq[(o + 2) * C_DIM + i], Wk[(o + 2) * C_DIM + j], a2);
        a3 = fmaf(Wq[(o + 3) * C_DIM + i], Wk[(o + 3) * C_DIM + j], a3);
    }
    float acc = (a0 + a1) + (a2 + a3);
    unsigned short h, l;
    split2(acc, h, l);
    Mh[i * C_DIM + j] = h;
    Ml[i * C_DIM + j] = l;
}

// ---------------------------------------------------------------------------
// K2 v11 = the round-2 structure (measured ~66 us) + conflict-free K staging.
// 256 thr = 4 waves; wave w owns i-rows [64w, 64w+64); pixel tile = 64.
// Per ks: stage M[256][32] hi/lo via coalesced uint4 streams into padded LDS
// (cooperative, COALESCED -- this is what r3..r10's per-wave global gathers
// destroyed); stage K[64px][32ch] hi/lo with ONE uint4 ds_write per thread
// (byte = 80p + 16jg -> start banks {0,4,..,28}, spans cover all 32 banks
// uniformly = floor rate; r2's uint-pair pattern was a non-uniform 8-way,
// 8.65M conflict cycles = ~21% of its time). Two plain barriers per ks.
// ---------------------------------------------------------------------------
__global__ __launch_bounds__(256) void score_kernel(
        const float* __restrict__ q, const float* __restrict__ k,
        const unsigned short* __restrict__ Mh,
        const unsigned short* __restrict__ Ml,
        float* __restrict__ score) {
    const int tid  = threadIdx.x;
    const int lane = tid & 63;
    const int w    = tid >> 6;          // 0..3
    const int pt   = blockIdx.x & 255;
    const int v    = blockIdx.x >> 8;
    const int gp0  = pt * PT;
    const int l15  = lane & 15;
    const int l4   = lane >> 4;
    const int p_s  = tid & 63;          // staging pixel (lane-fast)
    const int jg   = tid >> 6;          // staging channel group (8 ch)

    __shared__ __align__(16) unsigned short Mh_s[C_DIM * MROW];  // 20 KB
    __shared__ __align__(16) unsigned short Ml_s[C_DIM * MROW];  // 20 KB
    __shared__ __align__(16) unsigned short Kh_s[PT * MROW];     // 5 KB
    __shared__ __align__(16) unsigned short Kl_s[PT * MROW];     // 5 KB
    __shared__ float s_red[4][PT];                               // 1 KB

    const float* kv = k + (size_t)v * C_DIM * HW + gp0;
    const float* qv = q + (size_t)v * C_DIM * HW + gp0;

    f32x4 acc[4][4];
    #pragma unroll
    for (int a = 0; a < 4; ++a)
        #pragma unroll
        for (int b = 0; b < 4; ++b)
            acc[a][b] = (f32x4){0.f, 0.f, 0.f, 0.f};

    const int ibase = w * 64;

    for (int ks = 0; ks < C_DIM / BK; ++ks) {
        const int j0 = ks * BK;

        // --- stage M tile [256][32] hi/lo: coalesced uint4 streams ---
        #pragma unroll
        for (int e = 0; e < 4; ++e) {
            int cidx = tid + 256 * e;        // 0..1023 chunks of 8 elems
            int i  = cidx >> 2;              // row
            int jb = cidx & 3;               // 16B chunk in row
            uint4 mh = *(const uint4*)(Mh + i * C_DIM + j0 + jb * 8);
            uint4 ml = *(const uint4*)(Ml + i * C_DIM + j0 + jb * 8);
            *(uint4*)&Mh_s[i * MROW + jb * 8] = mh;
            *(uint4*)&Ml_s[i * MROW + jb * 8] = ml;
        }

        // --- stage K tile [64px][32ch] hi/lo: 8 coalesced loads, split,
        //     ONE uint4 ds_write per buffer (uniform banks) ---
        {
            const float* kp = kv + (size_t)(j0 + jg * 8) * HW + p_s;
            float x[8];
            #pragma unroll
            for (int e = 0; e < 8; ++e) x[e] = kp[(size_t)e * HW];
            unsigned short h[8], l[8];
            #pragma unroll
            for (int e = 0; e < 8; ++e) split2(x[e], h[e], l[e]);
            uint4 H, L;
            H.x = (unsigned)h[0] | ((unsigned)h[1] << 16);
            H.y = (unsigned)h[2] | ((unsigned)h[3] << 16);
            H.z = (unsigned)h[4] | ((unsigned)h[5] << 16);
            H.w = (unsigned)h[6] | ((unsigned)h[7] << 16);
            L.x = (unsigned)l[0] | ((unsigned)l[1] << 16);
            L.y = (unsigned)l[2] | ((unsigned)l[3] << 16);
            L.z = (unsigned)l[4] | ((unsigned)l[5] << 16);
            L.w = (unsigned)l[6] | ((unsigned)l[7] << 16);
            *(uint4*)&Kh_s[p_s * MROW + jg * 8] = H;
            *(uint4*)&Kl_s[p_s * MROW + jg * 8] = L;
        }
        __syncthreads();

        // --- fragments from LDS + 3-term MFMAs (r2 emission order) ---
        bf16x8 Ah[4], Al[4], Bh[4], Bl[4];
        #pragma unroll
        for (int it = 0; it < 4; ++it) {
            int ai = ibase + it * 16 + l15;
            Ah[it] = *(const bf16x8*)&Mh_s[ai * MROW + l4 * 8];
            Al[it] = *(const bf16x8*)&Ml_s[ai * MROW + l4 * 8];
        }
        #pragma unroll
        for (int jt = 0; jt < 4; ++jt) {
            int bp = jt * 16 + l15;
            Bh[jt] = *(const bf16x8*)&Kh_s[bp * MROW + l4 * 8];
            Bl[jt] = *(const bf16x8*)&Kl_s[bp * MROW + l4 * 8];
        }
        #pragma unroll
        for (int it = 0; it < 4; ++it)
            #pragma unroll
            for (int jt = 0; jt < 4; ++jt) {
                acc[it][jt] = __builtin_amdgcn_mfma_f32_16x16x32_bf16(
                                  Ah[it], Bh[jt], acc[it][jt], 0, 0, 0);
                acc[it][jt] = __builtin_amdgcn_mfma_f32_16x16x32_bf16(
                                  Ah[it], Bl[jt], acc[it][jt], 0, 0, 0);
                acc[it][jt] = __builtin_amdgcn_mfma_f32_16x16x32_bf16(
                                  Al[it], Bh[jt], acc[it][jt], 0, 0, 0);
            }
        __syncthreads();
    }

    // ---- epilogue: sp[p] = sum_i q[i,p] * T[i,p] (r2 exact) ----
    float sp[4];
    #pragma unroll
    for (int jt = 0; jt < 4; ++jt) sp[jt] = 0.f;
    #pragma unroll
    for (int jt = 0; jt < 4; ++jt) {
        #pragma unroll
        for (int it = 0; it < 4; ++it) {
            int irow = ibase + it * 16 + l4 * 4;
            const float* qp = qv + (size_t)irow * HW + jt * 16 + l15;
            #pragma unroll
            for (int r = 0; r < 4; ++r)
                sp[jt] = fmaf(qp[(size_t)r * HW], acc[it][jt][r], sp[jt]);
        }
        sp[jt] += __shfl_xor(sp[jt], 16, 64);
        sp[jt] += __shfl_xor(sp[jt], 32, 64);
    }
    if (lane < 16) {
        #pragma unroll
        for (int jt = 0; jt < 4; ++jt)
            s_red[w][jt * 16 + lane] = sp[jt];
    }
    __syncthreads();
    if (tid < PT) {
        score[v * HW + gp0 + tid] =
            s_red[0][tid] + s_red[1][tid] + s_red[2][tid] + s_red[3][tid];
    }
}

// ---------------------------------------------------------------------------
// K4: split Wv into bf16 hi/lo (reuses the Mh/Ml workspace).
// ---------------------------------------------------------------------------
__global__ void wsplit_kernel(const float* __restrict__ Wv,
                              unsigned short* __restrict__ Wvh,
                              unsigned short* __restrict__ Wvl) {
    const int i = blockIdx.x;
    const int j = threadIdx.x;
    unsigned short h, l;
    split2(Wv[i * C_DIM + j], h, l);
    Wvh[i * C_DIM + j] = h;
    Wvl[i * C_DIM + j] = l;
}

// ---------------------------------------------------------------------------
// K5 (unchanged from r9/r10): out = Wv @ vbar with inline softmax.  ~21 us
// vs ~19 us HBM floor -- not the bottleneck.
// ---------------------------------------------------------------------------
#define KROW 40
#define KT (PT * KROW)
__global__ __launch_bounds__(512, 2) void out_gemm_kernel(
        const float* __restrict__ vin,
        const unsigned short* __restrict__ Wvh,
        const unsigned short* __restrict__ Wvl,
        const float* __restrict__ score,
        float* __restrict__ out) {
    const int tid  = threadIdx.x;
    const int lane = tid & 63;
    const int w    = tid >> 6;          // 0..7
    const int gp0  = blockIdx.x * PT;
    const int l15  = lane & 15;
    const int l4   = lane >> 4;
    const int jg   = w;                 // staging channel group (4 ch)

    __shared__ __align__(16) unsigned short Xh_s[2][KT];
    __shared__ __align__(16) unsigned short Xl_s[2][KT];

    float wr[V_DIM];
    {
        float s[V_DIM];
        float mx = -1e30f;
        #pragma unroll
        for (int vv = 0; vv < V_DIM; ++vv) {
            s[vv] = score[vv * HW + gp0 + lane];
            mx = fmaxf(mx, s[vv]);
        }
        float sum = 0.f;
        #pragma unroll
        for (int vv = 0; vv < V_DIM; ++vv) {
            s[vv] = __expf(s[vv] - mx);
            sum += s[vv];
        }
        float inv = 1.0f / sum;
        #pragma unroll
        for (int vv = 0; vv < V_DIM; ++vv) wr[vv] = s[vv] * inv;
    }

    const float* vbase = vin + gp0 + lane;
    const int obase = w * 32;

    f32x4 acc[2][4];
    #pragma unroll
    for (int a = 0; a < 2; ++a)
        #pragma unroll
        for (int b = 0; b < 4; ++b)
            acc[a][b] = (f32x4){0.f, 0.f, 0.f, 0.f};

    float vx[2][4][V_DIM];
    bf16x8 Ah[2][2], Al[2][2];

    {
        float x0[4][V_DIM];
        #pragma unroll
        for (int vv = 0; vv < V_DIM; ++vv)
            #pragma unroll
            for (int e = 0; e < 4; ++e)
                x0[e][vv] = vbase[(size_t)(vv * C_DIM + jg * 4 + e) * HW];
        unsigned short h[4], l[4];
        #pragma unroll
        for (int e = 0; e < 4; ++e) {
            float s = 0.f;
            #pragma unroll
            for (int vv = 0; vv < V_DIM; ++vv) s = fmaf(wr[vv], x0[e][vv], s);
            split2(s, h[e], l[e]);
        }
        uint2 H, L;
        H.x = (unsigned)h[0] | ((unsigned)h[1] << 16);
        H.y = (unsigned)h[2] | ((unsigned)h[3] << 16);
        L.x = (unsigned)l[0] | ((unsigned)l[1] << 16);
        L.y = (unsigned)l[2] | ((unsigned)l[3] << 16);
        *(uint2*)&Xh_s[0][lane * KROW + jg * 4] = H;
        *(uint2*)&Xl_s[0][lane * KROW + jg * 4] = L;

        #pragma unroll
        for (int vv = 0; vv < V_DIM; ++vv)
            #pragma unroll
            for (int e = 0; e < 4; ++e)
                vx[1][e][vv] = vbase[(size_t)(vv * C_DIM + BK + jg * 4 + e) * HW];

        #pragma unroll
        for (int it = 0; it < 2; ++it) {
            int row = obase + it * 16 + l15;
            Ah[0][it] = *(const bf16x8*)(Wvh + (size_t)row * C_DIM + l4 * 8);
            Al[0][it] = *(const bf16x8*)(Wvl + (size_t)row * C_DIM + l4 * 8);
        }
    }
    __syncthreads();

    #pragma unroll
    for (int ks = 0; ks < 8; ++ks) {
        const int cur = ks & 1;

        if (ks < 7) {
            #pragma unroll
            for (int it = 0; it < 2; ++it) {
                int row = obase + it * 16 + l15;
                Ah[cur ^ 1][it] = *(const bf16x8*)(Wvh + (size_t)row * C_DIM +
                                                   (ks + 1) * BK + l4 * 8);
                Al[cur ^ 1][it] = *(const bf16x8*)(Wvl + (size_t)row * C_DIM +
                                                   (ks + 1) * BK + l4 * 8);
            }
        }
        if (ks < 6) {
            #pragma unroll
            for (int vv = 0; vv < V_DIM; ++vv)
                #pragma unroll
                for (int e = 0; e < 4; ++e)
                    vx[cur][e][vv] = vbase[(size_t)(vv * C_DIM + (ks + 2) * BK +
                                                    jg * 4 + e) * HW];
        }

        bf16x8 Bh[4], Bl[4];
        #pragma unroll
        for (int jt = 0; jt < 4; ++jt) {
            int bp = jt * 16 + l15;
            Bh[jt] = *(const bf16x8*)&Xh_s[cur][bp * KROW + l4 * 8];
            Bl[jt] = *(const bf16x8*)&Xl_s[cur][bp * KROW + l4 * 8];
        }
        #pragma unroll
        for (int it = 0; it < 2; ++it)
            #pragma unroll
            for (int jt = 0; jt < 4; ++jt)
                acc[it][jt] = __builtin_amdgcn_mfma_f32_16x16x32_bf16(
                                  Ah[cur][it], Bh[jt], acc[it][jt], 0, 0, 0);
        #pragma unroll
        for (int it = 0; it < 2; ++it)
            #pragma unroll
            for (int jt = 0; jt < 4; ++jt)
                acc[it][jt] = __builtin_amdgcn_mfma_f32_16x16x32_bf16(
                                  Ah[cur][it], Bl[jt], acc[it][jt], 0, 0, 0);
        #pragma unroll
        for (int it = 0; it < 2; ++it)
            #pragma unroll
            for (int jt = 0; jt < 4; ++jt)
                acc[it][jt] = __builtin_amdgcn_mfma_f32_16x16x32_bf16(
                                  Al[cur][it], Bh[jt], acc[it][jt], 0, 0, 0);

        if (ks < 7) {
            unsigned short h[4], l[4];
            #pragma unroll
            for (int e = 0; e < 4; ++e) {
                float s = 0.f;
                #pragma unroll
                for (int vv = 0; vv < V_DIM; ++vv)
                    s = fmaf(wr[vv], vx[cur ^ 1][e][vv], s);
                split2(s, h[e], l[e]);
            }
            uint2 H, L;
            H.x = (unsigned)h[0] | ((unsigned)h[1] << 16);
            H.y = (unsigned)h[2] | ((unsigned)h[3] << 16);
            L.x = (unsigned)l[0] | ((unsigned)l[1] << 16);
            L.y = (unsigned)l[2] | ((unsigned)l[3] << 16);
            *(uint2*)&Xh_s[cur ^ 1][lane * KROW + jg * 4] = H;
            *(uint2*)&Xl_s[cur ^ 1][lane * KROW + jg * 4] = L;
        }
        __syncthreads();
    }

    #pragma unroll
    for (int it = 0; it < 2; ++it)
        #pragma unroll
        for (int jt = 0; jt < 4; ++jt)
            #pragma unroll
            for (int r = 0; r < 4; ++r) {
                int o = obase + it * 16 + l4 * 4 + r;
                out[(size_t)o * HW + gp0 + jt * 16 + l15] = acc[it][jt][r];
            }
}

// ---------------------------------------------------------------------------
extern "C" void kernel_launch(void* const* d_in, const int* in_sizes, int n_in,
                              void* d_out, int out_size, void* d_ws, size_t ws_size,
                              hipStream_t stream) {
    const float* q  = (const float*)d_in[0];
    const float* k  = (const float*)d_in[1];
    const float* v  = (const float*)d_in[2];
    const float* Wq = (const float*)d_in[3];
    const float* Wk = (const float*)d_in[4];
    const float* Wv = (const float*)d_in[5];
    float* out = (float*)d_out;

    unsigned short* Mh = (unsigned short*)d_ws;          // 128 KB (later: Wvh)
    unsigned short* Ml = Mh + C_DIM * C_DIM;             // 128 KB (later: Wvl)
    float* score = (float*)(Ml + C_DIM * C_DIM);         // 384 KB

    compute_M_kernel<<<C_DIM, C_DIM, 0, stream>>>(Wq, Wk, Mh, Ml);
    score_kernel<<<V_DIM * 256, 256, 0, stream>>>(q, k, Mh, Ml, score);
    wsplit_kernel<<<C_DIM, C_DIM, 0, stream>>>(Wv, Mh, Ml);
    out_gemm_kernel<<<HW / PT, 512, 0, stream>>>(v, Mh, Ml, score, out);
}